// Round 4
// baseline (212.739 us; speedup 1.0000x reference)
//
#include <hip/hip_runtime.h>
#include <math.h>

#define JN 4096
#define CN 8192

typedef __attribute__((ext_vector_type(8))) short short8;
typedef __attribute__((ext_vector_type(4))) float f32x4;

// ---- d_ws layout (float offsets) ----
#define WS_LWT    0        // bf16 8192*64 = 262144 float slots (16B-aligned)
#define WS_ROWSUM 262144   // 4096
#define WS_DEG    266240   // 4096
#define WS_NORM   270336   // 4096
#define WS_X      274432   // 24576
#define WS_XN     299008   // 24576
#define WS_F1     323584   // 24576
#define WS_F1N    348160   // 24576
#define WS_F2     372736   // 24576
#define WS_GRES   397312   // 2

// ---- scratch inside the Poss half of d_out (float offsets within Poss) ----
// All consumed before k_valueB overwrites the Poss region; k_valueB reads
// nothing from this region -> no race, deterministic.
#define PS_BITR    0        // uint64[4096][64] = 2 MiB = 524288 float slots
#define PS_COLPART 524288   // 16*4096
#define PS_P1      589824   // 16*24576
#define PS_P2      983040   // 16*24576
#define PS_PART    1376256  // 2*2048

__device__ __forceinline__ unsigned short f2bf(float x) {
    unsigned int u = __float_as_uint(x);
    u += 0x7fffu + ((u >> 16) & 1u);   // RNE
    return (unsigned short)(u >> 16);
}

__device__ __forceinline__ float gt_val(const float* __restrict__ x, const float* __restrict__ a,
                                        const float* __restrict__ b, const float* __restrict__ tw,
                                        float acc, int f) {
#pragma unroll
    for (int k = 0; k < 6; ++k) acc += x[k] * tw[k * 64 + f];
#pragma unroll
    for (int k = 0; k < 6; ++k) acc += a[k] * tw[(k + 6) * 64 + f];
#pragma unroll
    for (int k = 0; k < 6; ++k) acc += b[k] * tw[(k + 12) * 64 + f];
    return acc;
}

// ---------- pass1: one float4 read of G -> rowsum + bit-packed left half ----------
// bit layout: col cu -> word (cu>>10)*16 + ((cu>>8)&3)*4 + (cu&3), bit (cu>>2)&63
__global__ __launch_bounds__(256) void k_pass1(const float* __restrict__ G, float* __restrict__ rowsum,
                                               unsigned long long* __restrict__ bitR) {
    int row = blockIdx.x;
    const float4* g4 = (const float4*)(G + (size_t)row * CN);
    int wv = threadIdx.x >> 6, lane = threadIdx.x & 63;
    unsigned long long* brow = bitR + (size_t)row * 64;
    float s = 0.f;
#pragma unroll
    for (int i = 0; i < 4; ++i) {          // left half: float4 idx 0..1023
        float4 v = g4[i * 256 + wv * 64 + lane];
        s += v.x + v.y + v.z + v.w;
        unsigned long long b0 = __ballot(v.x != 0.f);
        unsigned long long b1 = __ballot(v.y != 0.f);
        unsigned long long b2 = __ballot(v.z != 0.f);
        unsigned long long b3 = __ballot(v.w != 0.f);
        if (!lane) {
            int base = i * 16 + wv * 4;
            brow[base] = b0; brow[base + 1] = b1; brow[base + 2] = b2; brow[base + 3] = b3;
        }
    }
#pragma unroll
    for (int i = 4; i < 8; ++i) {          // right half: float4 idx 1024..2047
        float4 v = g4[i * 256 + wv * 64 + lane];
        s += v.x + v.y + v.z + v.w;
    }
    for (int o = 32; o; o >>= 1) s += __shfl_down(s, o, 64);
    __shared__ float lds[4];
    if (!lane) lds[wv] = s;
    __syncthreads();
    if (!threadIdx.x) rowsum[row] = lds[0] + lds[1] + lds[2] + lds[3];
}

// ---------- column sums from bitmask ----------
__global__ __launch_bounds__(256) void k_colsum_bits(const unsigned long long* __restrict__ bitR,
                                                     float* __restrict__ colpart) {
    __shared__ unsigned long long s_bits[256][4];
    int bx = blockIdx.x, r0 = blockIdx.y * 256;
    int tid = threadIdx.x;
    for (int t = tid; t < 1024; t += 256) {
        int r = t >> 2, wl = t & 3;
        s_bits[r][wl] = bitR[(size_t)(r0 + r) * 64 + bx * 4 + wl];
    }
    __syncthreads();
    int wl = tid & 3, bit = tid >> 2;
    int cnt = 0;
    for (int r = 0; r < 256; ++r)
        cnt += (int)((s_bits[r][wl] >> bit) & 1ull);
    colpart[(size_t)blockIdx.y * JN + bx * 256 + tid] = (float)cnt;
}

__global__ __launch_bounds__(256) void k_normred(const float* __restrict__ colpart,
                                                 float* __restrict__ deg, float* __restrict__ norm) {
    int j = blockIdx.x * 256 + threadIdx.x;
    float d = 0.f;
    for (int ch = 0; ch < 16; ++ch) d += colpart[(size_t)ch * JN + j];
    deg[j] = d;
    float dc = d < 1.f ? 1.f : d;
    norm[j] = rsqrtf(dc);
}

// ---------- rank (stable argsort(-h)) + build X, Xn ----------
__global__ __launch_bounds__(256) void k_rank(const float* __restrict__ h, const float* __restrict__ L,
                                              const float* __restrict__ Wp, const float* __restrict__ Pp,
                                              const float* __restrict__ Np,
                                              const float* __restrict__ norm,
                                              float* __restrict__ X, float* __restrict__ Xn) {
    int i = blockIdx.x;
    float hi = h[i];
    int cnt = 0;
    for (int j = threadIdx.x; j < JN; j += 256) {
        float hj = h[j];
        cnt += (hj > hi) || (hj == hi && j < i);
    }
    for (int o = 32; o; o >>= 1) cnt += __shfl_down(cnt, o, 64);
    __shared__ int lds[4];
    int lane = threadIdx.x & 63, w = threadIdx.x >> 6;
    if (!lane) lds[w] = cnt;
    __syncthreads();
    if (!threadIdx.x) {
        int r = lds[0] + lds[1] + lds[2] + lds[3];
        float n = norm[r];
        float x0 = hi, x1 = L[i], x2 = *Wp, x3 = *Pp, x4 = *Np, x5 = 1.f;
        float* xr = X + r * 6;
        xr[0] = x0; xr[1] = x1; xr[2] = x2; xr[3] = x3; xr[4] = x4; xr[5] = x5;
        float* xnr = Xn + r * 6;
        xnr[0] = x0 * n; xnr[1] = x1 * n; xnr[2] = x2 * n; xnr[3] = x3 * n; xnr[4] = x4 * n; xnr[5] = x5 * n;
    }
}

// ---------- propagation from bitmask: part[ch][c][k] ----------
__global__ __launch_bounds__(256) void k_prop_bits(const unsigned long long* __restrict__ bitR,
                                                   const float* __restrict__ in6, float* __restrict__ part) {
    __shared__ unsigned long long s_bits[256][4];
    __shared__ float s_in[256 * 6];
    int bx = blockIdx.x, r0 = blockIdx.y * 256;
    int tid = threadIdx.x;
    for (int t = tid; t < 1024; t += 256) {
        int r = t >> 2, wl = t & 3;
        s_bits[r][wl] = bitR[(size_t)(r0 + r) * 64 + bx * 4 + wl];
    }
    for (int t = tid; t < 1536; t += 256) s_in[t] = in6[r0 * 6 + t];
    __syncthreads();
    int wl = tid & 3, bit = tid >> 2;
    float a0 = 0, a1 = 0, a2 = 0, a3 = 0, a4 = 0, a5 = 0;
    for (int r = 0; r < 256; ++r) {
        float g = (float)((s_bits[r][wl] >> bit) & 1ull);
        const float* x = &s_in[r * 6];
        a0 += g * x[0]; a1 += g * x[1]; a2 += g * x[2];
        a3 += g * x[3]; a4 += g * x[4]; a5 += g * x[5];
    }
    float* o = part + ((size_t)blockIdx.y * JN + bx * 256 + tid) * 6;
    o[0] = a0; o[1] = a1; o[2] = a2; o[3] = a3; o[4] = a4; o[5] = a5;
}

__global__ __launch_bounds__(256) void k_fin1(const float* __restrict__ p1, const float* __restrict__ norm,
                                              float* __restrict__ f1, float* __restrict__ f1n) {
    int idx = blockIdx.x * 256 + threadIdx.x;  // < 24576
    float s = 0.f;
    for (int ch = 0; ch < 16; ++ch) s += p1[(size_t)ch * 24576 + idx];
    float n = norm[idx / 6];
    float v = s * n;
    f1[idx] = v;
    f1n[idx] = v * n;
}

__global__ __launch_bounds__(256) void k_fin2(const float* __restrict__ p2, const float* __restrict__ norm,
                                              float* __restrict__ f2) {
    int idx = blockIdx.x * 256 + threadIdx.x;
    float s = 0.f;
    for (int ch = 0; ch < 16; ++ch) s += p2[(size_t)ch * 24576 + idx];
    f2[idx] = s * norm[idx / 6];
}

// ---------- lin_w (64x8192 f32) -> lwT (8192x64 bf16) ----------
__global__ __launch_bounds__(256) void k_lwT(const float* __restrict__ lw, unsigned short* __restrict__ lwT) {
    __shared__ float s[64][65];
    int c0 = blockIdx.x * 64;
    for (int t = threadIdx.x; t < 4096; t += 256) {
        int f = t >> 6, cc = t & 63;
        s[f][cc] = lw[(size_t)f * CN + c0 + cc];
    }
    __syncthreads();
    for (int q = threadIdx.x; q < 512; q += 256) {
        int c = q >> 3, kc = q & 7;
        short8 pack;
#pragma unroll
        for (int i = 0; i < 8; ++i) pack[i] = (short)f2bf(s[kc * 8 + i][c]);
        *(short8*)(lwT + ((size_t)(c0 + c)) * 64 + kc * 8) = pack;
    }
}

// Shared GEMM body: stage lwT tile + recompute Gt tile, swapped-operand MFMA.
// A = lw cols (M=c), B = Gt rows (N=j)  =>  lane's 4 C-regs = 4 consecutive cols.
#define GEMM_PROLOGUE()                                                                   \
    __shared__ unsigned short sGt[64 * 64];                                               \
    __shared__ unsigned short sW[256 * 64];                                               \
    __shared__ float s_tw[18 * 64];                                                       \
    __shared__ float s_tb[64];                                                            \
    int j0 = blockIdx.y * 64, c0 = blockIdx.x * 256, tid = threadIdx.x;                   \
    for (int t = tid; t < 1152; t += 256) s_tw[t] = tw[t];                                \
    if (tid < 64) s_tb[tid] = tb[tid];                                                    \
    for (int q = tid; q < 2048; q += 256) {                                               \
        int col = q >> 3, off = q & 7;                                                    \
        short8 v = *(const short8*)(lwT + ((size_t)(c0 + col)) * 64 + off * 8);           \
        int byte = (col * 128 + off * 16) ^ ((col & 7) << 4);                             \
        *(short8*)((char*)sW + byte) = v;                                                 \
    }                                                                                     \
    __syncthreads();                                                                      \
    {                                                                                     \
        int row = tid & 63, fg = tid >> 6;                                                \
        const float* xr = X + (size_t)(j0 + row) * 6;                                     \
        const float* ar = f1 + (size_t)(j0 + row) * 6;                                    \
        const float* br = f2 + (size_t)(j0 + row) * 6;                                    \
        float xv[6], av[6], bv[6];                                                        \
        for (int k = 0; k < 6; ++k) { xv[k] = xr[k]; av[k] = ar[k]; bv[k] = br[k]; }      \
        short8 p0, p1v;                                                                   \
        for (int i = 0; i < 16; ++i) {                                                    \
            int f = fg * 16 + i;                                                          \
            float acc = gt_val(xv, av, bv, s_tw, s_tb[f], f);                             \
            unsigned short u = f2bf(acc);                                                 \
            if (i < 8) p0[i] = (short)u; else p1v[i - 8] = (short)u;                      \
        }                                                                                 \
        int base = row * 128 + fg * 32;                                                   \
        *(short8*)((char*)sGt + (base ^ ((row & 7) << 4))) = p0;                          \
        *(short8*)((char*)sGt + ((base + 16) ^ ((row & 7) << 4))) = p1v;                  \
    }                                                                                     \
    __syncthreads();                                                                      \
    int lane = tid & 63, w = tid >> 6;                                                    \
    int lrow = lane & 15, kg = lane >> 4;                                                 \
    f32x4 acc[4][4]; /* [m over c][n over j] */                                           \
    for (int m = 0; m < 4; ++m)                                                           \
        for (int n = 0; n < 4; ++n) acc[m][n] = (f32x4){0.f, 0.f, 0.f, 0.f};              \
    for (int ks = 0; ks < 2; ++ks) {                                                      \
        int kb = ks * 64 + kg * 16;                                                       \
        short8 wf[4], gf[4];                                                              \
        for (int m = 0; m < 4; ++m) {                                                     \
            int col = w * 64 + m * 16 + lrow;                                             \
            wf[m] = *(const short8*)((const char*)sW + ((col * 128 + kb) ^ ((col & 7) << 4))); \
        }                                                                                 \
        for (int n = 0; n < 4; ++n) {                                                     \
            int row = n * 16 + lrow;                                                      \
            gf[n] = *(const short8*)((const char*)sGt + ((row * 128 + kb) ^ ((row & 7) << 4))); \
        }                                                                                 \
        for (int m = 0; m < 4; ++m)                                                       \
            for (int n = 0; n < 4; ++n)                                                   \
                acc[m][n] = __builtin_amdgcn_mfma_f32_16x16x32_bf16(wf[m], gf[n], acc[m][n], 0, 0, 0); \
    }                                                                                     \
    bool left = (c0 < JN);                                                                \
    int cb[4]; f32x4 lb4[4], rsc4[4], dgc4[4];                                            \
    for (int m = 0; m < 4; ++m) {                                                         \
        cb[m] = c0 + w * 64 + m * 16 + kg * 4;                                            \
        lb4[m] = *(const f32x4*)&lb[cb[m]];                                               \
        if (left) { rsc4[m] = *(const f32x4*)&rowsum[cb[m]]; dgc4[m] = *(const f32x4*)&deg[cb[m]]; } \
        else      { rsc4[m] = (f32x4){0,0,0,0}; dgc4[m] = (f32x4){0,0,0,0}; }             \
    }

// ---------- pass A: Value write (float4) + two-pass softmax partials ----------
__global__ __launch_bounds__(256) void k_valueA(const float* __restrict__ X, const float* __restrict__ f1,
                                                const float* __restrict__ f2, const float* __restrict__ tw,
                                                const float* __restrict__ tb,
                                                const unsigned short* __restrict__ lwT,
                                                const float* __restrict__ lb,
                                                const float* __restrict__ rowsum, const float* __restrict__ deg,
                                                float* __restrict__ Value, float* __restrict__ partials) {
    GEMM_PROLOGUE()
    __shared__ float sRedM[4], sRedS[4];

    float mx = -INFINITY;
#pragma unroll
    for (int n = 0; n < 4; ++n) {
        int j = j0 + n * 16 + lrow;
        float rs_i = rowsum[j], dg_i = deg[j];
#pragma unroll
        for (int m = 0; m < 4; ++m) {
            f32x4 v4 = acc[m][n] + lb4[m];
            *(f32x4*)&Value[(size_t)j * CN + cb[m]] = v4;
            f32x4 t4;
#pragma unroll
            for (int u = 0; u < 4; ++u) {
                float om;
                if (left) {
                    bool m1 = ((rs_i + rsc4[m][u] + dg_i + dgc4[m][u]) == 0.0f) && (cb[m] + u > j);
                    om = m1 ? 0.f : 1.f;
                } else {
                    om = rs_i;
                }
                t4[u] = v4[u] - om * 10000.f;
            }
            acc[m][n] = t4;
            mx = fmaxf(fmaxf(fmaxf(mx, t4[0]), t4[1]), fmaxf(t4[2], t4[3]));
        }
    }
    float sm = 0.f;
#pragma unroll
    for (int n = 0; n < 4; ++n)
#pragma unroll
        for (int m = 0; m < 4; ++m)
#pragma unroll
            for (int u = 0; u < 4; ++u) sm += __expf(acc[m][n][u] - mx);

    for (int o = 32; o; o >>= 1) {
        float om_ = __shfl_down(mx, o, 64);
        float os_ = __shfl_down(sm, o, 64);
        float nm = fmaxf(mx, om_);
        sm = sm * __expf(mx - nm) + os_ * __expf(om_ - nm);
        mx = nm;
    }
    if (!lane) { sRedM[w] = mx; sRedS[w] = sm; }
    __syncthreads();
    if (!tid) {
        float M = sRedM[0], S = sRedS[0];
        for (int i = 1; i < 4; ++i) {
            float nm = fmaxf(M, sRedM[i]);
            S = S * __expf(M - nm) + sRedS[i] * __expf(sRedM[i] - nm);
            M = nm;
        }
        int bid = blockIdx.y * gridDim.x + blockIdx.x;
        partials[2 * bid] = M;
        partials[2 * bid + 1] = S;
    }
}

__global__ __launch_bounds__(256) void k_reduce(const float* __restrict__ partials, float* __restrict__ gres) {
    float mx = -INFINITY, sm = 0.f;
    for (int i = threadIdx.x; i < 2048; i += 256) {
        float m = partials[2 * i], s = partials[2 * i + 1];
        float nm = fmaxf(mx, m);
        sm = sm * __expf(mx - nm) + s * __expf(m - nm);
        mx = nm;
    }
    for (int o = 32; o; o >>= 1) {
        float om_ = __shfl_down(mx, o, 64);
        float os_ = __shfl_down(sm, o, 64);
        float nm = fmaxf(mx, om_);
        sm = sm * __expf(mx - nm) + os_ * __expf(om_ - nm);
        mx = nm;
    }
    __shared__ float sRedM[4], sRedS[4];
    int lane = threadIdx.x & 63, w = threadIdx.x >> 6;
    if (!lane) { sRedM[w] = mx; sRedS[w] = sm; }
    __syncthreads();
    if (!threadIdx.x) {
        float M = sRedM[0], S = sRedS[0];
        for (int i = 1; i < 4; ++i) {
            float nm = fmaxf(M, sRedM[i]);
            S = S * __expf(M - nm) + sRedS[i] * __expf(sRedM[i] - nm);
            M = nm;
        }
        gres[0] = M;
        gres[1] = S;
    }
}

// ---------- pass B: recompute GEMM, write Poss directly (float4) ----------
__global__ __launch_bounds__(256) void k_valueB(const float* __restrict__ X, const float* __restrict__ f1,
                                                const float* __restrict__ f2, const float* __restrict__ tw,
                                                const float* __restrict__ tb,
                                                const unsigned short* __restrict__ lwT,
                                                const float* __restrict__ lb,
                                                const float* __restrict__ rowsum, const float* __restrict__ deg,
                                                const float* __restrict__ gres, float* __restrict__ Poss) {
    GEMM_PROLOGUE()
    float gmax = gres[0];
    float ginv = 1.0f / gres[1];
#pragma unroll
    for (int n = 0; n < 4; ++n) {
        int j = j0 + n * 16 + lrow;
        float rs_i = rowsum[j], dg_i = deg[j];
#pragma unroll
        for (int m = 0; m < 4; ++m) {
            f32x4 v4 = acc[m][n] + lb4[m];
            f32x4 o4;
#pragma unroll
            for (int u = 0; u < 4; ++u) {
                float om;
                if (left) {
                    bool m1 = ((rs_i + rsc4[m][u] + dg_i + dgc4[m][u]) == 0.0f) && (cb[m] + u > j);
                    om = m1 ? 0.f : 1.f;
                } else {
                    om = rs_i;
                }
                o4[u] = __expf(v4[u] - om * 10000.f - gmax) * ginv;
            }
            *(f32x4*)&Poss[(size_t)j * CN + cb[m]] = o4;
        }
    }
}

extern "C" void kernel_launch(void* const* d_in, const int* in_sizes, int n_in,
                              void* d_out, int out_size, void* d_ws, size_t ws_size,
                              hipStream_t stream) {
    const float* h  = (const float*)d_in[0];
    const float* L  = (const float*)d_in[1];
    const float* W  = (const float*)d_in[2];
    const float* P  = (const float*)d_in[3];
    const float* N  = (const float*)d_in[4];
    const float* G  = (const float*)d_in[5];
    const float* tw = (const float*)d_in[6];
    const float* tb = (const float*)d_in[7];
    const float* lw = (const float*)d_in[8];
    const float* lb = (const float*)d_in[9];

    float* ws = (float*)d_ws;
    unsigned short* lwT = (unsigned short*)(ws + WS_LWT);
    float* rowsum = ws + WS_ROWSUM;
    float* deg    = ws + WS_DEG;
    float* norm   = ws + WS_NORM;
    float* X      = ws + WS_X;
    float* Xn     = ws + WS_XN;
    float* f1     = ws + WS_F1;
    float* f1n    = ws + WS_F1N;
    float* f2     = ws + WS_F2;
    float* gres   = ws + WS_GRES;

    float* Value = (float*)d_out;
    float* Poss  = Value + (size_t)JN * CN;

    unsigned long long* bitR = (unsigned long long*)(Poss + PS_BITR);
    float* colpart = Poss + PS_COLPART;
    float* p1      = Poss + PS_P1;
    float* p2      = Poss + PS_P2;
    float* part    = Poss + PS_PART;

    k_lwT        <<<128, 256, 0, stream>>>(lw, lwT);
    k_pass1      <<<JN, 256, 0, stream>>>(G, rowsum, bitR);
    k_colsum_bits<<<dim3(16, 16), 256, 0, stream>>>(bitR, colpart);
    k_normred    <<<16, 256, 0, stream>>>(colpart, deg, norm);
    k_rank       <<<JN, 256, 0, stream>>>(h, L, W, P, N, norm, X, Xn);
    k_prop_bits  <<<dim3(16, 16), 256, 0, stream>>>(bitR, Xn, p1);
    k_fin1       <<<96, 256, 0, stream>>>(p1, norm, f1, f1n);
    k_prop_bits  <<<dim3(16, 16), 256, 0, stream>>>(bitR, f1n, p2);
    k_fin2       <<<96, 256, 0, stream>>>(p2, norm, f2);
    k_valueA     <<<dim3(32, 64), 256, 0, stream>>>(X, f1, f2, tw, tb, lwT, lb, rowsum, deg, Value, part);
    k_reduce     <<<1, 256, 0, stream>>>(part, gres);
    k_valueB     <<<dim3(32, 64), 256, 0, stream>>>(X, f1, f2, tw, tb, lwT, lb, rowsum, deg, gres, Poss);
}

// Round 6
// 184.459 us; speedup vs baseline: 1.1533x; 1.1533x over previous
//
#include <hip/hip_runtime.h>
#include <math.h>

#define JN 4096
#define CN 8192

typedef __attribute__((ext_vector_type(8))) short short8;
typedef __attribute__((ext_vector_type(4))) float f32x4;

// ---- d_ws layout (float offsets) ----
#define WS_LWT    0        // bf16 8192*64 = 262144 float slots (16B-aligned)
#define WS_ROWSUM 262144   // 4096
#define WS_DEG    266240   // 4096
#define WS_NORM   270336   // 4096
#define WS_X      274432   // 24576
#define WS_F1     299008   // 24576
#define WS_F2     323584   // 24576
#define WS_PART   348160   // 2*2048 (valueB reads while Poss is being written -> keep in d_ws)

// ---- scratch inside the Poss half of d_out (float offsets within Poss) ----
// All consumed before k_valueB overwrites the Poss region; k_valueB reads
// nothing from this region -> no race, deterministic.
#define PS_BITR    0        // uint64[4096][64] = 2 MiB = 524288 float slots
#define PS_COLPART 524288   // 16*4096
#define PS_P1      589824   // 16*24576
#define PS_P2      983040   // 16*24576

__device__ __forceinline__ unsigned short f2bf(float x) {
    unsigned int u = __float_as_uint(x);
    u += 0x7fffu + ((u >> 16) & 1u);   // RNE
    return (unsigned short)(u >> 16);
}

__device__ __forceinline__ float gt_val(const float* __restrict__ x, const float* __restrict__ a,
                                        const float* __restrict__ b, const float* __restrict__ tw,
                                        float acc, int f) {
#pragma unroll
    for (int k = 0; k < 6; ++k) acc += x[k] * tw[k * 64 + f];
#pragma unroll
    for (int k = 0; k < 6; ++k) acc += a[k] * tw[(k + 6) * 64 + f];
#pragma unroll
    for (int k = 0; k < 6; ++k) acc += b[k] * tw[(k + 12) * 64 + f];
    return acc;
}

// ---------- front: pass1 (rowsum + bitpack) for blocks <4096, rank for the rest ----------
// bit layout: col cu -> word (cu>>10)*16 + ((cu>>8)&3)*4 + (cu&3), bit (cu>>2)&63
__global__ __launch_bounds__(256) void k_front(const float* __restrict__ G,
                                               const float* __restrict__ h, const float* __restrict__ L,
                                               const float* __restrict__ Wp, const float* __restrict__ Pp,
                                               const float* __restrict__ Np,
                                               float* __restrict__ rowsum,
                                               unsigned long long* __restrict__ bitR,
                                               float* __restrict__ X) {
    __shared__ float redf[4];
    __shared__ int redi[4];
    int wv = threadIdx.x >> 6, lane = threadIdx.x & 63;
    if (blockIdx.x < JN) {
        int row = blockIdx.x;
        const f32x4* g4 = (const f32x4*)(G + (size_t)row * CN);
        unsigned long long* brow = bitR + (size_t)row * 64;
        float s = 0.f;
#pragma unroll
        for (int i = 0; i < 4; ++i) {          // left half
            f32x4 v = __builtin_nontemporal_load(&g4[i * 256 + wv * 64 + lane]);
            s += v[0] + v[1] + v[2] + v[3];
            unsigned long long b0 = __ballot(v[0] != 0.f);
            unsigned long long b1 = __ballot(v[1] != 0.f);
            unsigned long long b2 = __ballot(v[2] != 0.f);
            unsigned long long b3 = __ballot(v[3] != 0.f);
            if (!lane) {
                int base = i * 16 + wv * 4;
                brow[base] = b0; brow[base + 1] = b1; brow[base + 2] = b2; brow[base + 3] = b3;
            }
        }
#pragma unroll
        for (int i = 4; i < 8; ++i) {          // right half
            f32x4 v = __builtin_nontemporal_load(&g4[i * 256 + wv * 64 + lane]);
            s += v[0] + v[1] + v[2] + v[3];
        }
        for (int o = 32; o; o >>= 1) s += __shfl_down(s, o, 64);
        if (!lane) redf[wv] = s;
        __syncthreads();
        if (!threadIdx.x) rowsum[row] = redf[0] + redf[1] + redf[2] + redf[3];
    } else {
        int i = blockIdx.x - JN;
        float hi = h[i];
        int cnt = 0;
        for (int j = threadIdx.x; j < JN; j += 256) {
            float hj = h[j];
            cnt += (hj > hi) || (hj == hi && j < i);   // stable argsort(-h) rank
        }
        for (int o = 32; o; o >>= 1) cnt += __shfl_down(cnt, o, 64);
        if (!lane) redi[wv] = cnt;
        __syncthreads();
        if (!threadIdx.x) {
            int r = redi[0] + redi[1] + redi[2] + redi[3];
            float* xr = X + r * 6;
            xr[0] = hi; xr[1] = L[i]; xr[2] = *Wp; xr[3] = *Pp; xr[4] = *Np; xr[5] = 1.f;
        }
    }
}

// ---------- column sums from bitmask ----------
__global__ __launch_bounds__(256) void k_colsum_bits(const unsigned long long* __restrict__ bitR,
                                                     float* __restrict__ colpart) {
    __shared__ unsigned long long s_bits[256][4];
    int bx = blockIdx.x, r0 = blockIdx.y * 256;
    int tid = threadIdx.x;
    for (int t = tid; t < 1024; t += 256) {
        int r = t >> 2, wl = t & 3;
        s_bits[r][wl] = bitR[(size_t)(r0 + r) * 64 + bx * 4 + wl];
    }
    __syncthreads();
    int wl = tid & 3, bit = tid >> 2;
    int cnt = 0;
    for (int r = 0; r < 256; ++r)
        cnt += (int)((s_bits[r][wl] >> bit) & 1ull);
    colpart[(size_t)blockIdx.y * JN + bx * 256 + tid] = (float)cnt;
}

__global__ __launch_bounds__(256) void k_normred(const float* __restrict__ colpart,
                                                 float* __restrict__ deg, float* __restrict__ norm) {
    int j = blockIdx.x * 256 + threadIdx.x;
    float d = 0.f;
    for (int ch = 0; ch < 16; ++ch) d += colpart[(size_t)ch * JN + j];
    deg[j] = d;
    float dc = d < 1.f ? 1.f : d;
    norm[j] = rsqrtf(dc);
}

// ---------- prop1: stage Xn = X*norm inline, emit p1 partials ----------
__global__ __launch_bounds__(256) void k_prop1(const unsigned long long* __restrict__ bitR,
                                               const float* __restrict__ X, const float* __restrict__ norm,
                                               float* __restrict__ part) {
    __shared__ unsigned long long s_bits[256][4];
    __shared__ float s_in[256 * 6];
    int bx = blockIdx.x, r0 = blockIdx.y * 256;
    int tid = threadIdx.x;
    for (int t = tid; t < 1024; t += 256) {
        int r = t >> 2, wl = t & 3;
        s_bits[r][wl] = bitR[(size_t)(r0 + r) * 64 + bx * 4 + wl];
    }
    for (int t = tid; t < 1536; t += 256) {
        int row = r0 + t / 6;
        s_in[t] = X[r0 * 6 + t] * norm[row];
    }
    __syncthreads();
    int wl = tid & 3, bit = tid >> 2;
    float a0 = 0, a1 = 0, a2 = 0, a3 = 0, a4 = 0, a5 = 0;
    for (int r = 0; r < 256; ++r) {
        float g = (float)((s_bits[r][wl] >> bit) & 1ull);
        const float* x = &s_in[r * 6];
        a0 += g * x[0]; a1 += g * x[1]; a2 += g * x[2];
        a3 += g * x[3]; a4 += g * x[4]; a5 += g * x[5];
    }
    float* o = part + ((size_t)blockIdx.y * JN + bx * 256 + tid) * 6;
    o[0] = a0; o[1] = a1; o[2] = a2; o[3] = a3; o[4] = a4; o[5] = a5;
}

// ---------- prop2: reduce p1 chunks + *norm inline (fin1 fused), emit p2; bx==0 writes f1 ----------
__global__ __launch_bounds__(256) void k_prop2(const unsigned long long* __restrict__ bitR,
                                               const float* __restrict__ p1, const float* __restrict__ norm,
                                               float* __restrict__ f1, float* __restrict__ part) {
    __shared__ unsigned long long s_bits[256][4];
    __shared__ float s_in[256 * 6];
    int bx = blockIdx.x, r0 = blockIdx.y * 256;
    int tid = threadIdx.x;
    for (int t = tid; t < 1024; t += 256) {
        int r = t >> 2, wl = t & 3;
        s_bits[r][wl] = bitR[(size_t)(r0 + r) * 64 + bx * 4 + wl];
    }
    for (int t = tid; t < 1536; t += 256) {
        float s = 0.f;
        for (int ch = 0; ch < 16; ++ch) s += p1[(size_t)ch * 24576 + r0 * 6 + t];
        int row = r0 + t / 6;
        float n = norm[row];
        float f1v = s * n;
        if (bx == 0) f1[r0 * 6 + t] = f1v;
        s_in[t] = f1v * n;
    }
    __syncthreads();
    int wl = tid & 3, bit = tid >> 2;
    float a0 = 0, a1 = 0, a2 = 0, a3 = 0, a4 = 0, a5 = 0;
    for (int r = 0; r < 256; ++r) {
        float g = (float)((s_bits[r][wl] >> bit) & 1ull);
        const float* x = &s_in[r * 6];
        a0 += g * x[0]; a1 += g * x[1]; a2 += g * x[2];
        a3 += g * x[3]; a4 += g * x[4]; a5 += g * x[5];
    }
    float* o = part + ((size_t)blockIdx.y * JN + bx * 256 + tid) * 6;
    o[0] = a0; o[1] = a1; o[2] = a2; o[3] = a3; o[4] = a4; o[5] = a5;
}

__global__ __launch_bounds__(256) void k_fin2(const float* __restrict__ p2, const float* __restrict__ norm,
                                              float* __restrict__ f2) {
    int idx = blockIdx.x * 256 + threadIdx.x;
    float s = 0.f;
    for (int ch = 0; ch < 16; ++ch) s += p2[(size_t)ch * 24576 + idx];
    f2[idx] = s * norm[idx / 6];
}

// ---------- lin_w (64x8192 f32) -> lwT (8192x64 bf16) ----------
__global__ __launch_bounds__(256) void k_lwT(const float* __restrict__ lw, unsigned short* __restrict__ lwT) {
    __shared__ float s[64][65];
    int c0 = blockIdx.x * 64;
    for (int t = threadIdx.x; t < 4096; t += 256) {
        int f = t >> 6, cc = t & 63;
        s[f][cc] = lw[(size_t)f * CN + c0 + cc];
    }
    __syncthreads();
    for (int q = threadIdx.x; q < 512; q += 256) {
        int c = q >> 3, kc = q & 7;
        short8 pack;
#pragma unroll
        for (int i = 0; i < 8; ++i) pack[i] = (short)f2bf(s[kc * 8 + i][c]);
        *(short8*)(lwT + ((size_t)(c0 + c)) * 64 + kc * 8) = pack;
    }
}

// Shared GEMM body: stage lwT tile + recompute Gt tile, swapped-operand MFMA.
// A = lw cols (M=c), B = Gt rows (N=j)  =>  lane's 4 C-regs = 4 consecutive cols.
#define GEMM_PROLOGUE()                                                                   \
    __shared__ unsigned short sGt[64 * 64];                                               \
    __shared__ unsigned short sW[256 * 64];                                               \
    __shared__ float s_tw[18 * 64];                                                       \
    __shared__ float s_tb[64];                                                            \
    int j0 = blockIdx.y * 64, c0 = blockIdx.x * 256, tid = threadIdx.x;                   \
    for (int t = tid; t < 1152; t += 256) s_tw[t] = tw[t];                                \
    if (tid < 64) s_tb[tid] = tb[tid];                                                    \
    for (int q = tid; q < 2048; q += 256) {                                               \
        int col = q >> 3, off = q & 7;                                                    \
        short8 v = *(const short8*)(lwT + ((size_t)(c0 + col)) * 64 + off * 8);           \
        int byte = (col * 128 + off * 16) ^ ((col & 7) << 4);                             \
        *(short8*)((char*)sW + byte) = v;                                                 \
    }                                                                                     \
    __syncthreads();                                                                      \
    {                                                                                     \
        int row = tid & 63, fg = tid >> 6;                                                \
        const float* xr = X + (size_t)(j0 + row) * 6;                                     \
        const float* ar = f1 + (size_t)(j0 + row) * 6;                                    \
        const float* br = f2 + (size_t)(j0 + row) * 6;                                    \
        float xv[6], av[6], bv[6];                                                        \
        for (int k = 0; k < 6; ++k) { xv[k] = xr[k]; av[k] = ar[k]; bv[k] = br[k]; }      \
        short8 p0, p1v;                                                                   \
        for (int i = 0; i < 16; ++i) {                                                    \
            int f = fg * 16 + i;                                                          \
            float acc = gt_val(xv, av, bv, s_tw, s_tb[f], f);                             \
            unsigned short u = f2bf(acc);                                                 \
            if (i < 8) p0[i] = (short)u; else p1v[i - 8] = (short)u;                      \
        }                                                                                 \
        int base = row * 128 + fg * 32;                                                   \
        *(short8*)((char*)sGt + (base ^ ((row & 7) << 4))) = p0;                          \
        *(short8*)((char*)sGt + ((base + 16) ^ ((row & 7) << 4))) = p1v;                  \
    }                                                                                     \
    __syncthreads();                                                                      \
    int lane = tid & 63, w = tid >> 6;                                                    \
    int lrow = lane & 15, kg = lane >> 4;                                                 \
    f32x4 acc[4][4]; /* [m over c][n over j] */                                           \
    for (int m = 0; m < 4; ++m)                                                           \
        for (int n = 0; n < 4; ++n) acc[m][n] = (f32x4){0.f, 0.f, 0.f, 0.f};              \
    for (int ks = 0; ks < 2; ++ks) {                                                      \
        int kb = ks * 64 + kg * 16;                                                       \
        short8 wf[4], gf[4];                                                              \
        for (int m = 0; m < 4; ++m) {                                                     \
            int col = w * 64 + m * 16 + lrow;                                             \
            wf[m] = *(const short8*)((const char*)sW + ((col * 128 + kb) ^ ((col & 7) << 4))); \
        }                                                                                 \
        for (int n = 0; n < 4; ++n) {                                                     \
            int row = n * 16 + lrow;                                                      \
            gf[n] = *(const short8*)((const char*)sGt + ((row * 128 + kb) ^ ((row & 7) << 4))); \
        }                                                                                 \
        for (int m = 0; m < 4; ++m)                                                       \
            for (int n = 0; n < 4; ++n)                                                   \
                acc[m][n] = __builtin_amdgcn_mfma_f32_16x16x32_bf16(wf[m], gf[n], acc[m][n], 0, 0, 0); \
    }                                                                                     \
    bool left = (c0 < JN);                                                                \
    int cb[4]; f32x4 lb4[4], rsc4[4], dgc4[4];                                            \
    for (int m = 0; m < 4; ++m) {                                                         \
        cb[m] = c0 + w * 64 + m * 16 + kg * 4;                                            \
        lb4[m] = *(const f32x4*)&lb[cb[m]];                                               \
        if (left) { rsc4[m] = *(const f32x4*)&rowsum[cb[m]]; dgc4[m] = *(const f32x4*)&deg[cb[m]]; } \
        else      { rsc4[m] = (f32x4){0,0,0,0}; dgc4[m] = (f32x4){0,0,0,0}; }             \
    }

// ---------- pass A: Value write (nt float4) + two-pass softmax partials ----------
__global__ __launch_bounds__(256) void k_valueA(const float* __restrict__ X, const float* __restrict__ f1,
                                                const float* __restrict__ f2, const float* __restrict__ tw,
                                                const float* __restrict__ tb,
                                                const unsigned short* __restrict__ lwT,
                                                const float* __restrict__ lb,
                                                const float* __restrict__ rowsum, const float* __restrict__ deg,
                                                float* __restrict__ Value, float* __restrict__ partials) {
    GEMM_PROLOGUE()
    __shared__ float sRedM[4], sRedS[4];

    float mx = -INFINITY;
#pragma unroll
    for (int n = 0; n < 4; ++n) {
        int j = j0 + n * 16 + lrow;
        float rs_i = rowsum[j], dg_i = deg[j];
#pragma unroll
        for (int m = 0; m < 4; ++m) {
            f32x4 v4 = acc[m][n] + lb4[m];
            __builtin_nontemporal_store(v4, (f32x4*)&Value[(size_t)j * CN + cb[m]]);
            f32x4 t4;
#pragma unroll
            for (int u = 0; u < 4; ++u) {
                float om;
                if (left) {
                    bool m1 = ((rs_i + rsc4[m][u] + dg_i + dgc4[m][u]) == 0.0f) && (cb[m] + u > j);
                    om = m1 ? 0.f : 1.f;
                } else {
                    om = rs_i;
                }
                t4[u] = v4[u] - om * 10000.f;
            }
            acc[m][n] = t4;
            mx = fmaxf(fmaxf(fmaxf(mx, t4[0]), t4[1]), fmaxf(t4[2], t4[3]));
        }
    }
    float sm = 0.f;
#pragma unroll
    for (int n = 0; n < 4; ++n)
#pragma unroll
        for (int m = 0; m < 4; ++m)
#pragma unroll
            for (int u = 0; u < 4; ++u) sm += __expf(acc[m][n][u] - mx);

    for (int o = 32; o; o >>= 1) {
        float om_ = __shfl_down(mx, o, 64);
        float os_ = __shfl_down(sm, o, 64);
        float nm = fmaxf(mx, om_);
        sm = sm * __expf(mx - nm) + os_ * __expf(om_ - nm);
        mx = nm;
    }
    if (!lane) { sRedM[w] = mx; sRedS[w] = sm; }
    __syncthreads();
    if (!tid) {
        float M = sRedM[0], S = sRedS[0];
        for (int i = 1; i < 4; ++i) {
            float nm = fmaxf(M, sRedM[i]);
            S = S * __expf(M - nm) + sRedS[i] * __expf(sRedM[i] - nm);
            M = nm;
        }
        int bid = blockIdx.y * gridDim.x + blockIdx.x;
        partials[2 * bid] = M;
        partials[2 * bid + 1] = S;
    }
}

// ---------- pass B: fused global softmax reduce + recompute GEMM, write Poss (nt float4) ----------
__global__ __launch_bounds__(256) void k_valueB(const float* __restrict__ X, const float* __restrict__ f1,
                                                const float* __restrict__ f2, const float* __restrict__ tw,
                                                const float* __restrict__ tb,
                                                const unsigned short* __restrict__ lwT,
                                                const float* __restrict__ lb,
                                                const float* __restrict__ rowsum, const float* __restrict__ deg,
                                                const float* __restrict__ partials, float* __restrict__ Poss) {
    // --- fused k_reduce: every block computes the identical (gmax, gsum) ---
    __shared__ float sRedM[4], sRedS[4], sG[2];
    {
        int tid0 = threadIdx.x;
        float mx = -INFINITY, sm = 0.f;
        for (int i = tid0; i < 2048; i += 256) {
            float m = partials[2 * i], s = partials[2 * i + 1];
            float nm = fmaxf(mx, m);
            sm = sm * __expf(mx - nm) + s * __expf(m - nm);
            mx = nm;
        }
        for (int o = 32; o; o >>= 1) {
            float om_ = __shfl_down(mx, o, 64);
            float os_ = __shfl_down(sm, o, 64);
            float nm = fmaxf(mx, om_);
            sm = sm * __expf(mx - nm) + os_ * __expf(om_ - nm);
            mx = nm;
        }
        int lane0 = tid0 & 63, w0 = tid0 >> 6;
        if (!lane0) { sRedM[w0] = mx; sRedS[w0] = sm; }
        __syncthreads();
        if (!tid0) {
            float M = sRedM[0], S = sRedS[0];
            for (int i = 1; i < 4; ++i) {
                float nm = fmaxf(M, sRedM[i]);
                S = S * __expf(M - nm) + sRedS[i] * __expf(sRedM[i] - nm);
                M = nm;
            }
            sG[0] = M; sG[1] = S;
        }
        __syncthreads();
    }
    float gmax = sG[0];
    float ginv = 1.0f / sG[1];

    GEMM_PROLOGUE()
#pragma unroll
    for (int n = 0; n < 4; ++n) {
        int j = j0 + n * 16 + lrow;
        float rs_i = rowsum[j], dg_i = deg[j];
#pragma unroll
        for (int m = 0; m < 4; ++m) {
            f32x4 v4 = acc[m][n] + lb4[m];
            f32x4 o4;
#pragma unroll
            for (int u = 0; u < 4; ++u) {
                float om;
                if (left) {
                    bool m1 = ((rs_i + rsc4[m][u] + dg_i + dgc4[m][u]) == 0.0f) && (cb[m] + u > j);
                    om = m1 ? 0.f : 1.f;
                } else {
                    om = rs_i;
                }
                o4[u] = __expf(v4[u] - om * 10000.f - gmax) * ginv;
            }
            __builtin_nontemporal_store(o4, (f32x4*)&Poss[(size_t)j * CN + cb[m]]);
        }
    }
}

extern "C" void kernel_launch(void* const* d_in, const int* in_sizes, int n_in,
                              void* d_out, int out_size, void* d_ws, size_t ws_size,
                              hipStream_t stream) {
    const float* h  = (const float*)d_in[0];
    const float* L  = (const float*)d_in[1];
    const float* W  = (const float*)d_in[2];
    const float* P  = (const float*)d_in[3];
    const float* N  = (const float*)d_in[4];
    const float* G  = (const float*)d_in[5];
    const float* tw = (const float*)d_in[6];
    const float* tb = (const float*)d_in[7];
    const float* lw = (const float*)d_in[8];
    const float* lb = (const float*)d_in[9];

    float* ws = (float*)d_ws;
    unsigned short* lwT = (unsigned short*)(ws + WS_LWT);
    float* rowsum = ws + WS_ROWSUM;
    float* deg    = ws + WS_DEG;
    float* norm   = ws + WS_NORM;
    float* X      = ws + WS_X;
    float* f1     = ws + WS_F1;
    float* f2     = ws + WS_F2;
    float* part   = ws + WS_PART;

    float* Value = (float*)d_out;
    float* Poss  = Value + (size_t)JN * CN;

    unsigned long long* bitR = (unsigned long long*)(Poss + PS_BITR);
    float* colpart = Poss + PS_COLPART;
    float* p1      = Poss + PS_P1;
    float* p2      = Poss + PS_P2;

    k_lwT        <<<128, 256, 0, stream>>>(lw, lwT);
    k_front      <<<2 * JN, 256, 0, stream>>>(G, h, L, W, P, N, rowsum, bitR, X);
    k_colsum_bits<<<dim3(16, 16), 256, 0, stream>>>(bitR, colpart);
    k_normred    <<<16, 256, 0, stream>>>(colpart, deg, norm);
    k_prop1      <<<dim3(16, 16), 256, 0, stream>>>(bitR, X, norm, p1);
    k_prop2      <<<dim3(16, 16), 256, 0, stream>>>(bitR, p1, norm, f1, p2);
    k_fin2       <<<96, 256, 0, stream>>>(p2, norm, f2);
    k_valueA     <<<dim3(32, 64), 256, 0, stream>>>(X, f1, f2, tw, tb, lwT, lb, rowsum, deg, Value, part);
    k_valueB     <<<dim3(32, 64), 256, 0, stream>>>(X, f1, f2, tw, tb, lwT, lb, rowsum, deg, part, Poss);
}

// Round 7
// 149.913 us; speedup vs baseline: 1.4191x; 1.2304x over previous
//
#include <hip/hip_runtime.h>
#include <math.h>

#define JN 4096
#define CN 8192

typedef __attribute__((ext_vector_type(8))) short short8;
typedef __attribute__((ext_vector_type(4))) float f32x4;

// ---- d_ws layout (float offsets) -- total 458752 floats = 1.75 MB ----
#define WS_LWT    0        // bf16 8192*64 = 262144 float slots
#define WS_GTB    262144   // bf16 4096*64 = 131072 float slots
#define WS_ROWSUM 393216   // 4096
#define WS_DEG    397312   // 4096
#define WS_NORM   401408   // 4096
#define WS_X      405504   // 24576
#define WS_F1     430080   // 24576
#define WS_PART   454656   // 2*2048 (valueB reads while Poss is being written -> ws)

// ---- scratch inside the Poss half of d_out (float offsets within Poss) ----
// All consumed before k_valueB overwrites the Poss region.
#define PS_BITR    0        // uint64[4096][64] = 2 MiB
#define PS_COLPART 524288   // 16*4096
#define PS_P1      589824   // 16*24576
#define PS_P2      983040   // 16*24576

__device__ __forceinline__ unsigned short f2bf(float x) {
    unsigned int u = __float_as_uint(x);
    u += 0x7fffu + ((u >> 16) & 1u);   // RNE
    return (unsigned short)(u >> 16);
}

__device__ __forceinline__ float gt_val(const float* __restrict__ x, const float* __restrict__ a,
                                        const float* __restrict__ b, const float* __restrict__ tw,
                                        float acc, int f) {
#pragma unroll
    for (int k = 0; k < 6; ++k) acc += x[k] * tw[k * 64 + f];
#pragma unroll
    for (int k = 0; k < 6; ++k) acc += a[k] * tw[(k + 6) * 64 + f];
#pragma unroll
    for (int k = 0; k < 6; ++k) acc += b[k] * tw[(k + 12) * 64 + f];
    return acc;
}

// ---------- front: G pass (rowsum+bitpack) | rank | lwT transpose ----------
// bit layout: col cu -> word (cu>>10)*16 + ((cu>>8)&3)*4 + (cu&3), bit (cu>>2)&63
__global__ __launch_bounds__(256) void k_front(const float* __restrict__ G,
                                               const float* __restrict__ h, const float* __restrict__ L,
                                               const float* __restrict__ Wp, const float* __restrict__ Pp,
                                               const float* __restrict__ Np,
                                               const float* __restrict__ lw,
                                               float* __restrict__ rowsum,
                                               unsigned long long* __restrict__ bitR,
                                               float* __restrict__ X,
                                               unsigned short* __restrict__ lwT) {
    __shared__ float redf[4];
    __shared__ int redi[4];
    __shared__ float s_t[64][65];
    int wv = threadIdx.x >> 6, lane = threadIdx.x & 63;
    if (blockIdx.x < JN) {
        int row = blockIdx.x;
        const f32x4* g4 = (const f32x4*)(G + (size_t)row * CN);
        unsigned long long* brow = bitR + (size_t)row * 64;
        float s = 0.f;
#pragma unroll
        for (int i = 0; i < 4; ++i) {          // left half
            f32x4 v = __builtin_nontemporal_load(&g4[i * 256 + wv * 64 + lane]);
            s += v[0] + v[1] + v[2] + v[3];
            unsigned long long b0 = __ballot(v[0] != 0.f);
            unsigned long long b1 = __ballot(v[1] != 0.f);
            unsigned long long b2 = __ballot(v[2] != 0.f);
            unsigned long long b3 = __ballot(v[3] != 0.f);
            if (!lane) {
                int base = i * 16 + wv * 4;
                brow[base] = b0; brow[base + 1] = b1; brow[base + 2] = b2; brow[base + 3] = b3;
            }
        }
#pragma unroll
        for (int i = 4; i < 8; ++i) {          // right half
            f32x4 v = __builtin_nontemporal_load(&g4[i * 256 + wv * 64 + lane]);
            s += v[0] + v[1] + v[2] + v[3];
        }
        for (int o = 32; o; o >>= 1) s += __shfl_down(s, o, 64);
        if (!lane) redf[wv] = s;
        __syncthreads();
        if (!threadIdx.x) rowsum[row] = redf[0] + redf[1] + redf[2] + redf[3];
    } else if (blockIdx.x < 2 * JN) {
        int i = blockIdx.x - JN;
        float hi = h[i];
        int cnt = 0;
        for (int j = threadIdx.x; j < JN; j += 256) {
            float hj = h[j];
            cnt += (hj > hi) || (hj == hi && j < i);   // stable argsort(-h) rank
        }
        for (int o = 32; o; o >>= 1) cnt += __shfl_down(cnt, o, 64);
        if (!lane) redi[wv] = cnt;
        __syncthreads();
        if (!threadIdx.x) {
            int r = redi[0] + redi[1] + redi[2] + redi[3];
            float* xr = X + r * 6;
            xr[0] = hi; xr[1] = L[i]; xr[2] = *Wp; xr[3] = *Pp; xr[4] = *Np; xr[5] = 1.f;
        }
    } else {
        int c0 = (blockIdx.x - 2 * JN) * 64;
        for (int t = threadIdx.x; t < 4096; t += 256) {
            int f = t >> 6, cc = t & 63;
            s_t[f][cc] = lw[(size_t)f * CN + c0 + cc];
        }
        __syncthreads();
        for (int q = threadIdx.x; q < 512; q += 256) {
            int c = q >> 3, kc = q & 7;
            short8 pack;
#pragma unroll
            for (int i = 0; i < 8; ++i) pack[i] = (short)f2bf(s_t[kc * 8 + i][c]);
            *(short8*)(lwT + ((size_t)(c0 + c)) * 64 + kc * 8) = pack;
        }
    }
}

// ---------- column sums from bitmask ----------
__global__ __launch_bounds__(256) void k_colsum_bits(const unsigned long long* __restrict__ bitR,
                                                     float* __restrict__ colpart) {
    __shared__ unsigned long long s_bits[256][4];
    int bx = blockIdx.x, r0 = blockIdx.y * 256;
    int tid = threadIdx.x;
    for (int t = tid; t < 1024; t += 256) {
        int r = t >> 2, wl = t & 3;
        s_bits[r][wl] = bitR[(size_t)(r0 + r) * 64 + bx * 4 + wl];
    }
    __syncthreads();
    int wl = tid & 3, bit = tid >> 2;
    int cnt = 0;
    for (int r = 0; r < 256; ++r)
        cnt += (int)((s_bits[r][wl] >> bit) & 1ull);
    colpart[(size_t)blockIdx.y * JN + bx * 256 + tid] = (float)cnt;
}

// ---------- prop1: inline norm from colpart, stage Xn, emit p1; bx==0 writes deg/norm ----------
__global__ __launch_bounds__(256) void k_prop1(const unsigned long long* __restrict__ bitR,
                                               const float* __restrict__ X,
                                               const float* __restrict__ colpart,
                                               float* __restrict__ deg, float* __restrict__ norm,
                                               float* __restrict__ part) {
    __shared__ unsigned long long s_bits[256][4];
    __shared__ float s_in[256 * 6];
    __shared__ float s_norm[256];
    int bx = blockIdx.x, r0 = blockIdx.y * 256;
    int tid = threadIdx.x;
    {
        float d = 0.f;
        for (int ch = 0; ch < 16; ++ch) d += colpart[(size_t)ch * JN + r0 + tid];
        float dc = d < 1.f ? 1.f : d;
        float nv = rsqrtf(dc);
        s_norm[tid] = nv;
        if (bx == 0) { deg[r0 + tid] = d; norm[r0 + tid] = nv; }
    }
    for (int t = tid; t < 1024; t += 256) {
        int r = t >> 2, wl = t & 3;
        s_bits[r][wl] = bitR[(size_t)(r0 + r) * 64 + bx * 4 + wl];
    }
    __syncthreads();
    for (int t = tid; t < 1536; t += 256)
        s_in[t] = X[r0 * 6 + t] * s_norm[t / 6];
    __syncthreads();
    int wl = tid & 3, bit = tid >> 2;
    float a0 = 0, a1 = 0, a2 = 0, a3 = 0, a4 = 0, a5 = 0;
    for (int r = 0; r < 256; ++r) {
        float g = (float)((s_bits[r][wl] >> bit) & 1ull);
        const float* x = &s_in[r * 6];
        a0 += g * x[0]; a1 += g * x[1]; a2 += g * x[2];
        a3 += g * x[3]; a4 += g * x[4]; a5 += g * x[5];
    }
    float* o = part + ((size_t)blockIdx.y * JN + bx * 256 + tid) * 6;
    o[0] = a0; o[1] = a1; o[2] = a2; o[3] = a3; o[4] = a4; o[5] = a5;
}

// ---------- prop2: reduce p1 + *norm inline, emit p2; bx==0 writes f1 ----------
__global__ __launch_bounds__(256) void k_prop2(const unsigned long long* __restrict__ bitR,
                                               const float* __restrict__ p1, const float* __restrict__ norm,
                                               float* __restrict__ f1, float* __restrict__ part) {
    __shared__ unsigned long long s_bits[256][4];
    __shared__ float s_in[256 * 6];
    int bx = blockIdx.x, r0 = blockIdx.y * 256;
    int tid = threadIdx.x;
    for (int t = tid; t < 1024; t += 256) {
        int r = t >> 2, wl = t & 3;
        s_bits[r][wl] = bitR[(size_t)(r0 + r) * 64 + bx * 4 + wl];
    }
    for (int t = tid; t < 1536; t += 256) {
        float s = 0.f;
        for (int ch = 0; ch < 16; ++ch) s += p1[(size_t)ch * 24576 + r0 * 6 + t];
        int row = r0 + t / 6;
        float n = norm[row];
        float f1v = s * n;
        if (bx == 0) f1[r0 * 6 + t] = f1v;
        s_in[t] = f1v * n;
    }
    __syncthreads();
    int wl = tid & 3, bit = tid >> 2;
    float a0 = 0, a1 = 0, a2 = 0, a3 = 0, a4 = 0, a5 = 0;
    for (int r = 0; r < 256; ++r) {
        float g = (float)((s_bits[r][wl] >> bit) & 1ull);
        const float* x = &s_in[r * 6];
        a0 += g * x[0]; a1 += g * x[1]; a2 += g * x[2];
        a3 += g * x[3]; a4 += g * x[4]; a5 += g * x[5];
    }
    float* o = part + ((size_t)blockIdx.y * JN + bx * 256 + tid) * 6;
    o[0] = a0; o[1] = a1; o[2] = a2; o[3] = a3; o[4] = a4; o[5] = a5;
}

// ---------- Gt: reduce p2 -> f2 rows inline, compute Gtb bf16 (once) ----------
__global__ __launch_bounds__(256) void k_gt(const float* __restrict__ p2, const float* __restrict__ norm,
                                            const float* __restrict__ f1, const float* __restrict__ X,
                                            const float* __restrict__ tw, const float* __restrict__ tb,
                                            unsigned short* __restrict__ Gtb) {
    __shared__ float s_x[64 * 6], s_f1[64 * 6], s_f2[64 * 6];
    __shared__ float s_tw[18 * 64], s_tb[64];
    int j0 = blockIdx.x * 64, tid = threadIdx.x;
    for (int t = tid; t < 1152; t += 256) s_tw[t] = tw[t];
    if (tid < 64) s_tb[tid] = tb[tid];
    for (int t = tid; t < 384; t += 256) {
        s_x[t] = X[j0 * 6 + t];
        s_f1[t] = f1[j0 * 6 + t];
        float s = 0.f;
        for (int ch = 0; ch < 16; ++ch) s += p2[(size_t)ch * 24576 + j0 * 6 + t];
        s_f2[t] = s * norm[j0 + t / 6];
    }
    __syncthreads();
    int row = tid & 63, fg = tid >> 6;
    float xv[6], av[6], bv[6];
#pragma unroll
    for (int k = 0; k < 6; ++k) {
        xv[k] = s_x[row * 6 + k]; av[k] = s_f1[row * 6 + k]; bv[k] = s_f2[row * 6 + k];
    }
    short8 p0, p1v;
#pragma unroll
    for (int i = 0; i < 16; ++i) {
        int f = fg * 16 + i;
        float acc = gt_val(xv, av, bv, s_tw, s_tb[f], f);
        unsigned short u = f2bf(acc);
        if (i < 8) p0[i] = (short)u; else p1v[i - 8] = (short)u;
    }
    *(short8*)(Gtb + (size_t)(j0 + row) * 64 + fg * 16) = p0;
    *(short8*)(Gtb + (size_t)(j0 + row) * 64 + fg * 16 + 8) = p1v;
}

// Shared GEMM body: stage lwT + Gtb tiles (swizzled), swapped-operand MFMA.
// A = lw cols (M=c), B = Gt rows (N=j)  =>  lane's 4 C-regs = 4 consecutive cols.
#define GEMM_PROLOGUE()                                                                   \
    __shared__ unsigned short sGt[64 * 64];                                               \
    __shared__ unsigned short sW[256 * 64];                                               \
    int j0 = blockIdx.y * 64, c0 = blockIdx.x * 256, tid = threadIdx.x;                   \
    for (int q = tid; q < 2048; q += 256) {                                               \
        int col = q >> 3, off = q & 7;                                                    \
        short8 v = *(const short8*)(lwT + ((size_t)(c0 + col)) * 64 + off * 8);           \
        int byte = (col * 128 + off * 16) ^ ((col & 7) << 4);                             \
        *(short8*)((char*)sW + byte) = v;                                                 \
    }                                                                                     \
    for (int q = tid; q < 512; q += 256) {                                                \
        int row = q >> 3, off = q & 7;                                                    \
        short8 v = *(const short8*)(Gtb + ((size_t)(j0 + row)) * 64 + off * 8);           \
        int byte = (row * 128 + off * 16) ^ ((row & 7) << 4);                             \
        *(short8*)((char*)sGt + byte) = v;                                                \
    }                                                                                     \
    __syncthreads();                                                                      \
    int lane = tid & 63, w = tid >> 6;                                                    \
    int lrow = lane & 15, kg = lane >> 4;                                                 \
    f32x4 acc[4][4]; /* [m over c][n over j] */                                           \
    for (int m = 0; m < 4; ++m)                                                           \
        for (int n = 0; n < 4; ++n) acc[m][n] = (f32x4){0.f, 0.f, 0.f, 0.f};              \
    for (int ks = 0; ks < 2; ++ks) {                                                      \
        int kb = ks * 64 + kg * 16;                                                       \
        short8 wf[4], gf[4];                                                              \
        for (int m = 0; m < 4; ++m) {                                                     \
            int col = w * 64 + m * 16 + lrow;                                             \
            wf[m] = *(const short8*)((const char*)sW + ((col * 128 + kb) ^ ((col & 7) << 4))); \
        }                                                                                 \
        for (int n = 0; n < 4; ++n) {                                                     \
            int row = n * 16 + lrow;                                                      \
            gf[n] = *(const short8*)((const char*)sGt + ((row * 128 + kb) ^ ((row & 7) << 4))); \
        }                                                                                 \
        for (int m = 0; m < 4; ++m)                                                       \
            for (int n = 0; n < 4; ++n)                                                   \
                acc[m][n] = __builtin_amdgcn_mfma_f32_16x16x32_bf16(wf[m], gf[n], acc[m][n], 0, 0, 0); \
    }                                                                                     \
    bool left = (c0 < JN);                                                                \
    int cb[4]; f32x4 lb4[4], rsc4[4], dgc4[4];                                            \
    for (int m = 0; m < 4; ++m) {                                                         \
        cb[m] = c0 + w * 64 + m * 16 + kg * 4;                                            \
        lb4[m] = *(const f32x4*)&lb[cb[m]];                                               \
        if (left) { rsc4[m] = *(const f32x4*)&rowsum[cb[m]]; dgc4[m] = *(const f32x4*)&deg[cb[m]]; } \
        else      { rsc4[m] = (f32x4){0,0,0,0}; dgc4[m] = (f32x4){0,0,0,0}; }             \
    }

// ---------- pass A: Value write (nt float4) + two-pass softmax partials ----------
__global__ __launch_bounds__(256) void k_valueA(const unsigned short* __restrict__ Gtb,
                                                const unsigned short* __restrict__ lwT,
                                                const float* __restrict__ lb,
                                                const float* __restrict__ rowsum, const float* __restrict__ deg,
                                                float* __restrict__ Value, float* __restrict__ partials) {
    GEMM_PROLOGUE()
    __shared__ float sRedM[4], sRedS[4];

    float mx = -INFINITY;
#pragma unroll
    for (int n = 0; n < 4; ++n) {
        int j = j0 + n * 16 + lrow;
        float rs_i = rowsum[j], dg_i = deg[j];
#pragma unroll
        for (int m = 0; m < 4; ++m) {
            f32x4 v4 = acc[m][n] + lb4[m];
            __builtin_nontemporal_store(v4, (f32x4*)&Value[(size_t)j * CN + cb[m]]);
            f32x4 t4;
#pragma unroll
            for (int u = 0; u < 4; ++u) {
                float om;
                if (left) {
                    bool m1 = ((rs_i + rsc4[m][u] + dg_i + dgc4[m][u]) == 0.0f) && (cb[m] + u > j);
                    om = m1 ? 0.f : 1.f;
                } else {
                    om = rs_i;
                }
                t4[u] = v4[u] - om * 10000.f;
            }
            acc[m][n] = t4;
            mx = fmaxf(fmaxf(fmaxf(mx, t4[0]), t4[1]), fmaxf(t4[2], t4[3]));
        }
    }
    float sm = 0.f;
#pragma unroll
    for (int n = 0; n < 4; ++n)
#pragma unroll
        for (int m = 0; m < 4; ++m)
#pragma unroll
            for (int u = 0; u < 4; ++u) sm += __expf(acc[m][n][u] - mx);

    for (int o = 32; o; o >>= 1) {
        float om_ = __shfl_down(mx, o, 64);
        float os_ = __shfl_down(sm, o, 64);
        float nm = fmaxf(mx, om_);
        sm = sm * __expf(mx - nm) + os_ * __expf(om_ - nm);
        mx = nm;
    }
    if (!lane) { sRedM[w] = mx; sRedS[w] = sm; }
    __syncthreads();
    if (!tid) {
        float M = sRedM[0], S = sRedS[0];
        for (int i = 1; i < 4; ++i) {
            float nm = fmaxf(M, sRedM[i]);
            S = S * __expf(M - nm) + sRedS[i] * __expf(sRedM[i] - nm);
            M = nm;
        }
        int bid = blockIdx.y * gridDim.x + blockIdx.x;
        partials[2 * bid] = M;
        partials[2 * bid + 1] = S;
    }
}

// ---------- pass B: fused global softmax reduce + GEMM, write Poss (nt float4) ----------
__global__ __launch_bounds__(256) void k_valueB(const unsigned short* __restrict__ Gtb,
                                                const unsigned short* __restrict__ lwT,
                                                const float* __restrict__ lb,
                                                const float* __restrict__ rowsum, const float* __restrict__ deg,
                                                const float* __restrict__ partials, float* __restrict__ Poss) {
    // --- fused reduce: every block computes the identical (gmax, gsum) ---
    __shared__ float sRedM[4], sRedS[4], sG[2];
    {
        int tid0 = threadIdx.x;
        float mx = -INFINITY, sm = 0.f;
        for (int i = tid0; i < 2048; i += 256) {
            float m = partials[2 * i], s = partials[2 * i + 1];
            float nm = fmaxf(mx, m);
            sm = sm * __expf(mx - nm) + s * __expf(m - nm);
            mx = nm;
        }
        for (int o = 32; o; o >>= 1) {
            float om_ = __shfl_down(mx, o, 64);
            float os_ = __shfl_down(sm, o, 64);
            float nm = fmaxf(mx, om_);
            sm = sm * __expf(mx - nm) + os_ * __expf(om_ - nm);
            mx = nm;
        }
        int lane0 = tid0 & 63, w0 = tid0 >> 6;
        if (!lane0) { sRedM[w0] = mx; sRedS[w0] = sm; }
        __syncthreads();
        if (!tid0) {
            float M = sRedM[0], S = sRedS[0];
            for (int i = 1; i < 4; ++i) {
                float nm = fmaxf(M, sRedM[i]);
                S = S * __expf(M - nm) + sRedS[i] * __expf(sRedM[i] - nm);
                M = nm;
            }
            sG[0] = M; sG[1] = S;
        }
        __syncthreads();
    }
    float gmax = sG[0];
    float ginv = 1.0f / sG[1];

    GEMM_PROLOGUE()
#pragma unroll
    for (int n = 0; n < 4; ++n) {
        int j = j0 + n * 16 + lrow;
        float rs_i = rowsum[j], dg_i = deg[j];
#pragma unroll
        for (int m = 0; m < 4; ++m) {
            f32x4 v4 = acc[m][n] + lb4[m];
            f32x4 o4;
#pragma unroll
            for (int u = 0; u < 4; ++u) {
                float om;
                if (left) {
                    bool m1 = ((rs_i + rsc4[m][u] + dg_i + dgc4[m][u]) == 0.0f) && (cb[m] + u > j);
                    om = m1 ? 0.f : 1.f;
                } else {
                    om = rs_i;
                }
                o4[u] = __expf(v4[u] - om * 10000.f - gmax) * ginv;
            }
            __builtin_nontemporal_store(o4, (f32x4*)&Poss[(size_t)j * CN + cb[m]]);
        }
    }
}

extern "C" void kernel_launch(void* const* d_in, const int* in_sizes, int n_in,
                              void* d_out, int out_size, void* d_ws, size_t ws_size,
                              hipStream_t stream) {
    const float* h  = (const float*)d_in[0];
    const float* L  = (const float*)d_in[1];
    const float* W  = (const float*)d_in[2];
    const float* P  = (const float*)d_in[3];
    const float* N  = (const float*)d_in[4];
    const float* G  = (const float*)d_in[5];
    const float* tw = (const float*)d_in[6];
    const float* tb = (const float*)d_in[7];
    const float* lw = (const float*)d_in[8];
    const float* lb = (const float*)d_in[9];

    float* ws = (float*)d_ws;
    unsigned short* lwT = (unsigned short*)(ws + WS_LWT);
    unsigned short* Gtb = (unsigned short*)(ws + WS_GTB);
    float* rowsum = ws + WS_ROWSUM;
    float* deg    = ws + WS_DEG;
    float* norm   = ws + WS_NORM;
    float* X      = ws + WS_X;
    float* f1     = ws + WS_F1;
    float* part   = ws + WS_PART;

    float* Value = (float*)d_out;
    float* Poss  = Value + (size_t)JN * CN;

    unsigned long long* bitR = (unsigned long long*)(Poss + PS_BITR);
    float* colpart = Poss + PS_COLPART;
    float* p1      = Poss + PS_P1;
    float* p2      = Poss + PS_P2;

    k_front      <<<2 * JN + 128, 256, 0, stream>>>(G, h, L, W, P, N, lw, rowsum, bitR, X, lwT);
    k_colsum_bits<<<dim3(16, 16), 256, 0, stream>>>(bitR, colpart);
    k_prop1      <<<dim3(16, 16), 256, 0, stream>>>(bitR, X, colpart, deg, norm, p1);
    k_prop2      <<<dim3(16, 16), 256, 0, stream>>>(bitR, p1, norm, f1, p2);
    k_gt         <<<64, 256, 0, stream>>>(p2, norm, f1, X, tw, tb, Gtb);
    k_valueA     <<<dim3(32, 64), 256, 0, stream>>>(Gtb, lwT, lb, rowsum, deg, Value, part);
    k_valueB     <<<dim3(32, 64), 256, 0, stream>>>(Gtb, lwT, lb, rowsum, deg, part, Poss);
}